// Round 8
// baseline (1145.736 us; speedup 1.0000x reference)
//
#include <hip/hip_runtime.h>
#include <cstdint>
#include <cstddef>

// ---------------------------------------------------------------------------
// TreeModel: hierarchical bi-GRU (sentence + doc) + MLP head. Round 8:
//   - dw_prep: doc h-weights pre-packed to f16 in MFMA fragment order
//     [dir][frag(48)][tid(512)][e(8)] -> doc_gru weight load becomes 48
//     fully-coalesced b128 loads/thread (round-7 doc_gru was BOUND by an
//     8MB strided f32 weight fetch at 30 GB/s = ~250us).
//   - sent_gru: h_f f32 mirror dropped (h reconstructed from hi/lo planes),
//     LDS 84->75KB -> 2 blocks/CU (__launch_bounds__(256,2)).
//   - emb_gemm, xproj_gemm, mlp_head unchanged.
// ---------------------------------------------------------------------------

typedef __attribute__((ext_vector_type(8))) short bf16x8;     // 8 bf16 = 4 VGPR
typedef __attribute__((ext_vector_type(8))) _Float16 f16x8;   // 8 f16  = 4 VGPR
typedef __attribute__((ext_vector_type(4))) float f32x4;      // C/D frag

__device__ __forceinline__ void split_bf16(float f, short& hi, short& lo) {
  unsigned u = __float_as_uint(f);
  unsigned rb = (u + 0x7FFFu + ((u >> 16) & 1u)) & 0xFFFF0000u;  // RNE
  hi = (short)(rb >> 16);
  float r = f - __uint_as_float(rb);
  unsigned ur = __float_as_uint(r);
  lo = (short)((ur + 0x7FFFu + ((ur >> 16) & 1u)) >> 16);
}

__device__ __forceinline__ float bf2f(short s) {
  return __uint_as_float(((unsigned)(unsigned short)s) << 16);
}

__device__ __forceinline__ float sigm(float x) { return 1.f / (1.f + __expf(-x)); }
__device__ __forceinline__ float tanh_fast(float x) {
  float e = __expf(2.f * x);
  return 1.f - 2.f / (e + 1.f);
}

// Build transposed, split-bf16 B for embProj: Bt[n][k], n in [0,768), k in [0,128)
__global__ void bt_prep(const float* __restrict__ sWg_f, const float* __restrict__ sWc_f,
                        const float* __restrict__ sWg_b, const float* __restrict__ sWc_b,
                        short* __restrict__ BtHi, short* __restrict__ BtLo) {
  int i = blockIdx.x * 256 + threadIdx.x;
  if (i >= 768 * 128) return;
  int n = i >> 7, k = i & 127;
  float f;
  if (n < 256) f = sWg_f[k * 256 + n];
  else if (n < 384) f = sWc_f[k * 128 + (n - 256)];
  else if (n < 640) f = sWg_b[k * 256 + (n - 384)];
  else f = sWc_b[k * 128 + (n - 640)];
  short hi, lo;
  split_bf16(f, hi, lo);
  BtHi[i] = hi;
  BtLo[i] = lo;
}

// Transposed split-bf16 planes of doc x-part weights: PdT[n][k], n in [0,1536),
// k in [0,256). n layout: [dWg_f 512 | dWc_f 256 | dWg_b 512 | dWc_b 256].
__global__ void packdt_prep(const float* __restrict__ dWg_f, const float* __restrict__ dWc_f,
                            const float* __restrict__ dWg_b, const float* __restrict__ dWc_b,
                            short* __restrict__ Hi, short* __restrict__ Lo) {
  int i = blockIdx.x * 256 + threadIdx.x;
  if (i >= 1536 * 256) return;
  int n = i >> 8, k = i & 255;
  float f;
  if (n < 512) f = dWg_f[k * 512 + n];
  else if (n < 768) f = dWc_f[k * 256 + (n - 512)];
  else if (n < 1280) f = dWg_b[k * 512 + (n - 768)];
  else f = dWc_b[k * 256 + (n - 1280)];
  short hi, lo;
  split_bf16(f, hi, lo);
  Hi[i] = hi;
  Lo[i] = lo;
}

// Doc h-part weights -> f16, fragment-ordered: DW[dir][f(48)][tid(512)][e(8)].
// tid = 64w+16g+li. f<32: nt=f>>3,kk=f&7, src=dWg[(256+32kk+8g+e)*512+64w+16nt+li]
//                   f>=32: ct,kk,      src=dWc[(256+32kk+8g+e)*256+32w+16ct+li]
__global__ void dw_prep(const float* __restrict__ dWg_f, const float* __restrict__ dWc_f,
                        const float* __restrict__ dWg_b, const float* __restrict__ dWc_b,
                        short* __restrict__ DW) {
  int i = blockIdx.x * 256 + threadIdx.x;   // 2*48*512*8 = 393216
  if (i >= 393216) return;
  int e = i & 7;
  int tid = (i >> 3) & 511;
  int f = (i >> 12) & 63;   // 48 frags -> fits in 6 bits
  int dir = i >> 12 >= 48 ? 1 : 0;
  f = (i >> 12) - dir * 48;
  int w = tid >> 6, g = (tid >> 4) & 3, li = tid & 15;
  const float* Wg = dir ? dWg_b : dWg_f;
  const float* Wc = dir ? dWc_b : dWc_f;
  float v;
  if (f < 32) {
    int nt = f >> 3, kk = f & 7;
    v = Wg[(size_t)(256 + 32 * kk + 8 * g + e) * 512 + 64 * w + 16 * nt + li];
  } else {
    int q = f - 32, ct = q >> 3, kk = q & 7;
    v = Wc[(size_t)(256 + 32 * kk + 8 * g + e) * 256 + 32 * w + 16 * ct + li];
  }
  DW[i] = __builtin_bit_cast(short, (_Float16)v);
}

// ---------------------------------------------------------------------------
// embProj[50000,768] = emb[50000,128] @ packS[128,768], MFMA 3-pass split-bf16.
// ---------------------------------------------------------------------------
__global__ __launch_bounds__(256, 1) void emb_gemm(
    const float* __restrict__ emb, const short* __restrict__ BtHi,
    const short* __restrict__ BtLo, float* __restrict__ C) {
  const int tid = threadIdx.x;
  const int w = tid >> 6, l = tid & 63, li = l & 15, g = l >> 4;
  const int m0 = blockIdx.x * 64;

  bf16x8 ahi[4][4], alo[4][4];
#pragma unroll
  for (int mt = 0; mt < 4; ++mt) {
    int row = m0 + 16 * mt + li;
    if (row > 49999) row = 49999;
    const float* ap = emb + (size_t)row * 128 + 8 * g;
#pragma unroll
    for (int kk = 0; kk < 4; ++kk) {
      float4 v0 = *(const float4*)(ap + 32 * kk);
      float4 v1 = *(const float4*)(ap + 32 * kk + 4);
      float vv[8] = {v0.x, v0.y, v0.z, v0.w, v1.x, v1.y, v1.z, v1.w};
#pragma unroll
      for (int e = 0; e < 8; ++e) {
        short hi, lo;
        split_bf16(vv[e], hi, lo);
        ahi[mt][kk][e] = hi;
        alo[mt][kk][e] = lo;
      }
    }
  }

  f32x4 acc[4][12];
#pragma unroll
  for (int mt = 0; mt < 4; ++mt)
#pragma unroll
    for (int nt = 0; nt < 12; ++nt) acc[mt][nt] = (f32x4){0.f, 0.f, 0.f, 0.f};

#pragma unroll
  for (int nt = 0; nt < 12; ++nt) {
    const int col = 192 * w + 16 * nt + li;
    const short* bh = BtHi + col * 128 + 8 * g;
    const short* bl = BtLo + col * 128 + 8 * g;
    bf16x8 bhi[4], blo[4];
#pragma unroll
    for (int kk = 0; kk < 4; ++kk) {
      bhi[kk] = *(const bf16x8*)(bh + 32 * kk);
      blo[kk] = *(const bf16x8*)(bl + 32 * kk);
    }
#pragma unroll
    for (int kk = 0; kk < 4; ++kk)
#pragma unroll
      for (int mt = 0; mt < 4; ++mt) {
        acc[mt][nt] = __builtin_amdgcn_mfma_f32_16x16x32_bf16(alo[mt][kk], bhi[kk], acc[mt][nt], 0, 0, 0);
        acc[mt][nt] = __builtin_amdgcn_mfma_f32_16x16x32_bf16(ahi[mt][kk], blo[kk], acc[mt][nt], 0, 0, 0);
        acc[mt][nt] = __builtin_amdgcn_mfma_f32_16x16x32_bf16(ahi[mt][kk], bhi[kk], acc[mt][nt], 0, 0, 0);
      }
  }

#pragma unroll
  for (int mt = 0; mt < 4; ++mt)
#pragma unroll
    for (int nt = 0; nt < 12; ++nt) {
      const int col = 192 * w + 16 * nt + li;
#pragma unroll
      for (int r = 0; r < 4; ++r) {
        int row = m0 + 16 * mt + 4 * g + r;
        if (row < 50000) C[(size_t)row * 768 + col] = acc[mt][nt][r];
      }
    }
}

// ---------------------------------------------------------------------------
// xprojD[2048,1536] = sent[2048,256] @ packD[256,1536], MFMA 3-pass split-bf16.
// ---------------------------------------------------------------------------
__global__ __launch_bounds__(256, 1) void xproj_gemm(
    const short* __restrict__ AHi, const short* __restrict__ ALo,
    const short* __restrict__ BtHi, const short* __restrict__ BtLo,
    float* __restrict__ C) {
  const int tid = threadIdx.x;
  const int w = tid >> 6, l = tid & 63, li = l & 15, g = l >> 4;
  const int m0 = blockIdx.x * 64;
  const int n0 = blockIdx.y * 512 + 128 * w;

  f32x4 acc[4][8];
#pragma unroll
  for (int mt = 0; mt < 4; ++mt)
#pragma unroll
    for (int nt = 0; nt < 8; ++nt) acc[mt][nt] = (f32x4){0.f, 0.f, 0.f, 0.f};

#pragma unroll
  for (int kk = 0; kk < 8; ++kk) {
    bf16x8 ah[4], al[4];
#pragma unroll
    for (int mt = 0; mt < 4; ++mt) {
      const int row = m0 + 16 * mt + li;
      ah[mt] = *(const bf16x8*)&AHi[(size_t)row * 256 + 32 * kk + 8 * g];
      al[mt] = *(const bf16x8*)&ALo[(size_t)row * 256 + 32 * kk + 8 * g];
    }
#pragma unroll
    for (int nt = 0; nt < 8; ++nt) {
      const int col = n0 + 16 * nt + li;
      bf16x8 bh = *(const bf16x8*)&BtHi[(size_t)col * 256 + 32 * kk + 8 * g];
      bf16x8 bl = *(const bf16x8*)&BtLo[(size_t)col * 256 + 32 * kk + 8 * g];
#pragma unroll
      for (int mt = 0; mt < 4; ++mt) {
        acc[mt][nt] = __builtin_amdgcn_mfma_f32_16x16x32_bf16(al[mt], bh, acc[mt][nt], 0, 0, 0);
        acc[mt][nt] = __builtin_amdgcn_mfma_f32_16x16x32_bf16(ah[mt], bl, acc[mt][nt], 0, 0, 0);
        acc[mt][nt] = __builtin_amdgcn_mfma_f32_16x16x32_bf16(ah[mt], bh, acc[mt][nt], 0, 0, 0);
      }
    }
  }

#pragma unroll
  for (int mt = 0; mt < 4; ++mt)
#pragma unroll
    for (int nt = 0; nt < 8; ++nt) {
      const int col = n0 + 16 * nt + li;
#pragma unroll
      for (int r = 0; r < 4; ++r) {
        int row = m0 + 16 * mt + 4 * g + r;
        C[(size_t)row * 1536 + col] = acc[mt][nt][r];
      }
    }
}

// ---------------------------------------------------------------------------
// Sentence GRU, MFMA. grid (128,2), block 256, 2 blocks/CU (LDS 75KB).
// h carried as bf16 hi/lo planes only (f32 mirror dropped).
// ---------------------------------------------------------------------------
#define SENTS 16

__global__ __launch_bounds__(256, 2) void sent_gru(
    const int* __restrict__ X, const int* __restrict__ L,
    const float* __restrict__ embProj,
    const float* __restrict__ Wg_f, const float* __restrict__ bg_f,
    const float* __restrict__ Wc_f, const float* __restrict__ bc_f,
    const float* __restrict__ Wg_b, const float* __restrict__ bg_b,
    const float* __restrict__ Wc_b, const float* __restrict__ bc_b,
    short* __restrict__ sentHi, short* __restrict__ sentLo) {
  const int dir = blockIdx.y;
  const int g0 = blockIdx.x * SENTS;
  const int tid = threadIdx.x;
  const int w = tid >> 6, l = tid & 63;
  const int li = l & 15, g = l >> 4;
  const float* Wg = dir ? Wg_b : Wg_f;
  const float* Wc = dir ? Wc_b : Wc_f;
  const float* bgp = dir ? bg_b : bg_f;
  const float* bcp = dir ? bc_b : bc_f;

  __shared__ float xbuf[2][SENTS][384];
  __shared__ float u_f[SENTS][132];
  alignas(16) __shared__ short h_hi[SENTS][136], h_lo[SENTS][136];
  alignas(16) __shared__ short rh_hi[SENTS][136], rh_lo[SENTS][136];
  __shared__ int wid[2][SENTS];
  __shared__ int len_s[SENTS];

  bf16x8 bgh[4][4], bgl[4][4];
  bf16x8 bch[2][4], bcl[2][4];
#pragma unroll
  for (int nt = 0; nt < 4; ++nt)
#pragma unroll
    for (int kk = 0; kk < 4; ++kk) {
      const float* base = Wg + (size_t)(128 + 32 * kk + 8 * g) * 256 + 64 * w + 16 * nt + li;
#pragma unroll
      for (int e = 0; e < 8; ++e) {
        short hi, lo;
        split_bf16(base[(size_t)e * 256], hi, lo);
        bgh[nt][kk][e] = hi; bgl[nt][kk][e] = lo;
      }
    }
#pragma unroll
  for (int ct = 0; ct < 2; ++ct)
#pragma unroll
    for (int kk = 0; kk < 4; ++kk) {
      const float* base = Wc + (size_t)(128 + 32 * kk + 8 * g) * 128 + 32 * w + 16 * ct + li;
#pragma unroll
      for (int e = 0; e < 8; ++e) {
        short hi, lo;
        split_bf16(base[(size_t)e * 128], hi, lo);
        bch[ct][kk][e] = hi; bcl[ct][kk][e] = lo;
      }
    }
  float bgj[4], bcj[2];
#pragma unroll
  for (int nt = 0; nt < 4; ++nt) bgj[nt] = bgp[64 * w + 16 * nt + li];
#pragma unroll
  for (int ct = 0; ct < 2; ++ct) bcj[ct] = bcp[32 * w + 16 * ct + li];

  if (tid < SENTS) {
    int ll = L[g0 + tid];
    len_s[tid] = ll;
    wid[0][tid] = X[(g0 + tid) * 64 + (dir ? (ll - 1) : 0)];
    wid[1][tid] = (1 < ll) ? X[(g0 + tid) * 64 + (dir ? (ll - 2) : 1)] : 0;
  }
  for (int q = tid; q < SENTS * 136; q += 256) {
    ((short*)h_hi)[q] = 0; ((short*)h_lo)[q] = 0;
  }
  __syncthreads();

  int lens4[4];
#pragma unroll
  for (int r = 0; r < 4; ++r) lens4[r] = len_s[4 * g + r];
  int maxlen = 0;
#pragma unroll
  for (int m = 0; m < SENTS; ++m) maxlen = max(maxlen, len_s[m]);

  auto prefetch_x = [&](int t) {
    int b = t & 1;
#pragma unroll
    for (int c = 0; c < 6; ++c) {
      int q = tid + 256 * c;
      int m = q / 96, s = q - m * 96;
      const float* src = embProj + (size_t)wid[b][m] * 768 + dir * 384 + s * 4;
      float* dst = (float*)&xbuf[b][0][0] + q * 4;
      __builtin_amdgcn_global_load_lds(
          (const __attribute__((address_space(1))) void*)src,
          (__attribute__((address_space(3))) void*)dst, 16, 0, 0);
    }
  };

  prefetch_x(0);
  __syncthreads();

  for (int t = 0; t < maxlen; ++t) {
    const int cur = t & 1;
    prefetch_x(t + 1);
    if (tid < SENTS) {
      int ll = len_s[tid], tt = t + 2;
      wid[tt & 1][tid] = (tt < ll) ? X[(g0 + tid) * 64 + (dir ? (ll - 1 - tt) : tt)] : 0;
    }

    bf16x8 a_hi[4], a_lo[4];
#pragma unroll
    for (int kk = 0; kk < 4; ++kk) {
      a_hi[kk] = *(const bf16x8*)&h_hi[li][32 * kk + 8 * g];
      a_lo[kk] = *(const bf16x8*)&h_lo[li][32 * kk + 8 * g];
    }
    f32x4 accg[4];
#pragma unroll
    for (int nt = 0; nt < 4; ++nt) {
      const int col = 64 * w + 16 * nt + li;
      f32x4 c;
#pragma unroll
      for (int r = 0; r < 4; ++r) c[r] = bgj[nt] + xbuf[cur][4 * g + r][col];
#pragma unroll
      for (int kk = 0; kk < 4; ++kk) {
        c = __builtin_amdgcn_mfma_f32_16x16x32_bf16(a_hi[kk], bgh[nt][kk], c, 0, 0, 0);
        c = __builtin_amdgcn_mfma_f32_16x16x32_bf16(a_hi[kk], bgl[nt][kk], c, 0, 0, 0);
        c = __builtin_amdgcn_mfma_f32_16x16x32_bf16(a_lo[kk], bgh[nt][kk], c, 0, 0, 0);
      }
      accg[nt] = c;
    }
    if (w < 2) {
#pragma unroll
      for (int nt = 0; nt < 4; ++nt) {
        const int col = 64 * w + 16 * nt + li;
#pragma unroll
        for (int r = 0; r < 4; ++r) {
          const int row = 4 * g + r;
          float s = sigm(accg[nt][r]);
          float hold = bf2f(h_hi[row][col]) + bf2f(h_lo[row][col]);
          float rh = s * hold;
          short hi, lo;
          split_bf16(rh, hi, lo);
          rh_hi[row][col] = hi;
          rh_lo[row][col] = lo;
        }
      }
    } else {
#pragma unroll
      for (int nt = 0; nt < 4; ++nt) {
        const int col = 64 * (w - 2) + 16 * nt + li;
#pragma unroll
        for (int r = 0; r < 4; ++r) {
          u_f[4 * g + r][col] = sigm(accg[nt][r]);
        }
      }
    }
    __syncthreads();

    bf16x8 ra_hi[4], ra_lo[4];
#pragma unroll
    for (int kk = 0; kk < 4; ++kk) {
      ra_hi[kk] = *(const bf16x8*)&rh_hi[li][32 * kk + 8 * g];
      ra_lo[kk] = *(const bf16x8*)&rh_lo[li][32 * kk + 8 * g];
    }
#pragma unroll
    for (int ct = 0; ct < 2; ++ct) {
      const int col = 32 * w + 16 * ct + li;
      f32x4 c;
#pragma unroll
      for (int r = 0; r < 4; ++r) c[r] = bcj[ct] + xbuf[cur][4 * g + r][256 + col];
#pragma unroll
      for (int kk = 0; kk < 4; ++kk) {
        c = __builtin_amdgcn_mfma_f32_16x16x32_bf16(ra_hi[kk], bch[ct][kk], c, 0, 0, 0);
        c = __builtin_amdgcn_mfma_f32_16x16x32_bf16(ra_hi[kk], bcl[ct][kk], c, 0, 0, 0);
        c = __builtin_amdgcn_mfma_f32_16x16x32_bf16(ra_lo[kk], bch[ct][kk], c, 0, 0, 0);
      }
#pragma unroll
      for (int r = 0; r < 4; ++r) {
        const int row = 4 * g + r;
        float cand = tanh_fast(c[r]);
        float u = u_f[row][col];
        float hold = bf2f(h_hi[row][col]) + bf2f(h_lo[row][col]);
        float hn = u * hold + (1.f - u) * cand;
        hn = (t < lens4[r]) ? hn : hold;
        short hi, lo;
        split_bf16(hn, hi, lo);
        h_hi[row][col] = hi;
        h_lo[row][col] = lo;
      }
    }
    __syncthreads();
  }

  for (int q = tid; q < SENTS * 128; q += 256) {
    int m = q >> 7, j = q & 127;
    size_t o = (size_t)(g0 + m) * 256 + dir * 128 + j;
    sentHi[o] = h_hi[m][j];
    sentLo[o] = h_lo[m][j];
  }
}

// ---------------------------------------------------------------------------
// Doc GRU, f16 MFMA v5. grid (4, 2), block 512 = 8 waves. 16 docs/block.
// Weights loaded from fragment-ordered f16 pack (48 coalesced b128 / thread).
// ---------------------------------------------------------------------------
#define DOCS 16

__global__ __launch_bounds__(512, 1) void doc_gru_mfma(
    const float* __restrict__ xprojD, const int* __restrict__ L2,
    const short* __restrict__ DW,
    const float* __restrict__ dbg_f, const float* __restrict__ dbc_f,
    const float* __restrict__ dbg_b, const float* __restrict__ dbc_b,
    float* __restrict__ docv) {
  const int dir = blockIdx.y;
  const int g0 = blockIdx.x * DOCS;
  const int tid = threadIdx.x;
  const int w = tid >> 6, l = tid & 63, li = l & 15, g = l >> 4;
  const float* bgp = dir ? dbg_b : dbg_f;
  const float* bcp = dir ? dbc_b : dbc_f;
  const int xoff = dir ? 768 : 0;

  alignas(16) __shared__ short h_hi[DOCS][264];
  alignas(16) __shared__ short rh_hi[DOCS][264];
  __shared__ float h_f[DOCS][256], u_f[DOCS][256];
  __shared__ int len_s[DOCS];

  // ---- one-time: fragment-ordered f16 weights, fully coalesced ----
  f16x8 wg[4][8];   // gates: [nt][kk]
  f16x8 wc[2][8];   // cand:  [ct][kk]
  const short* DWp = DW + (size_t)dir * 48 * 512 * 8;
#pragma unroll
  for (int nt = 0; nt < 4; ++nt)
#pragma unroll
    for (int kk = 0; kk < 8; ++kk) {
      int f = nt * 8 + kk;
      wg[nt][kk] = *(const f16x8*)&DWp[((size_t)f * 512 + tid) * 8];
      asm volatile("" : "+v"(wg[nt][kk]));
    }
#pragma unroll
  for (int ct = 0; ct < 2; ++ct)
#pragma unroll
    for (int kk = 0; kk < 8; ++kk) {
      int f = 32 + ct * 8 + kk;
      wc[ct][kk] = *(const f16x8*)&DWp[((size_t)f * 512 + tid) * 8];
      asm volatile("" : "+v"(wc[ct][kk]));
    }
  float bgj[4], bcj[2];
#pragma unroll
  for (int nt = 0; nt < 4; ++nt) bgj[nt] = bgp[64 * w + 16 * nt + li];
#pragma unroll
  for (int ct = 0; ct < 2; ++ct) bcj[ct] = bcp[32 * w + 16 * ct + li];

  if (tid < DOCS) len_s[tid] = L2[g0 + tid];
  for (int q = tid; q < DOCS * 264; q += 512) ((short*)h_hi)[q] = 0;
  for (int q = tid; q < DOCS * 256; q += 512) {
    ((float*)h_f)[q] = 0.f; ((float*)u_f)[q] = 0.f;
  }
  __syncthreads();

  int lens4[4];
#pragma unroll
  for (int r = 0; r < 4; ++r) lens4[r] = len_s[4 * g + r];
  int maxlen = 0;
#pragma unroll
  for (int m = 0; m < DOCS; ++m) maxlen = max(maxlen, len_s[m]);

  auto xrow = [&](int r, int t) -> size_t {
    int ti = dir ? max(lens4[r] - 1 - t, 0) : min(t, 31);
    return ((size_t)(g0 + 4 * g + r) * 32 + ti) * 1536 + xoff;
  };

  float xg[16], xc[8], xgn[16], xcn[8];
#pragma unroll
  for (int r = 0; r < 4; ++r) {
    size_t xb = xrow(r, 0);
#pragma unroll
    for (int nt = 0; nt < 4; ++nt) xg[nt * 4 + r] = xprojD[xb + 64 * w + 16 * nt + li];
#pragma unroll
    for (int ct = 0; ct < 2; ++ct) xc[ct * 4 + r] = xprojD[xb + 512 + 32 * w + 16 * ct + li];
  }

  for (int t = 0; t < maxlen; ++t) {
    f32x4 acc[4];
#pragma unroll
    for (int nt = 0; nt < 4; ++nt)
#pragma unroll
      for (int r = 0; r < 4; ++r) acc[nt][r] = bgj[nt] + xg[nt * 4 + r];
    f32x4 acc2[2];
#pragma unroll
    for (int ct = 0; ct < 2; ++ct)
#pragma unroll
      for (int r = 0; r < 4; ++r) acc2[ct][r] = bcj[ct] + xc[ct * 4 + r];

#pragma unroll
    for (int r = 0; r < 4; ++r) {
      size_t xb = xrow(r, t + 1);
#pragma unroll
      for (int nt = 0; nt < 4; ++nt) xgn[nt * 4 + r] = xprojD[xb + 64 * w + 16 * nt + li];
#pragma unroll
      for (int ct = 0; ct < 2; ++ct) xcn[ct * 4 + r] = xprojD[xb + 512 + 32 * w + 16 * ct + li];
    }

#pragma unroll
    for (int c = 0; c < 8; ++c) {
      f16x8 ah = *(const f16x8*)&h_hi[li][32 * c + 8 * g];
#pragma unroll
      for (int nt = 0; nt < 4; ++nt)
        acc[nt] = __builtin_amdgcn_mfma_f32_16x16x32_f16(ah, wg[nt][c], acc[nt], 0, 0, 0);
    }
    if (w < 4) {
#pragma unroll
      for (int nt = 0; nt < 4; ++nt) {
        const int col = 64 * w + 16 * nt + li;
#pragma unroll
        for (int r = 0; r < 4; ++r) {
          const int m = 4 * g + r;
          float s = sigm(acc[nt][r]);
          float rh = s * h_f[m][col];
          rh_hi[m][col] = __builtin_bit_cast(short, (_Float16)rh);
        }
      }
    } else {
#pragma unroll
      for (int nt = 0; nt < 4; ++nt) {
        const int col = 64 * (w - 4) + 16 * nt + li;
#pragma unroll
        for (int r = 0; r < 4; ++r) u_f[4 * g + r][col] = sigm(acc[nt][r]);
      }
    }
    __syncthreads();

#pragma unroll
    for (int c = 0; c < 8; ++c) {
      f16x8 rah = *(const f16x8*)&rh_hi[li][32 * c + 8 * g];
#pragma unroll
      for (int ct = 0; ct < 2; ++ct)
        acc2[ct] = __builtin_amdgcn_mfma_f32_16x16x32_f16(rah, wc[ct][c], acc2[ct], 0, 0, 0);
    }
#pragma unroll
    for (int ct = 0; ct < 2; ++ct) {
      const int col = 32 * w + 16 * ct + li;
#pragma unroll
      for (int r = 0; r < 4; ++r) {
        const int m = 4 * g + r;
        float cand = tanh_fast(acc2[ct][r]);
        float u = u_f[m][col];
        float hold = h_f[m][col];
        float hn = u * hold + (1.f - u) * cand;
        hn = (t < lens4[r]) ? hn : hold;
        h_f[m][col] = hn;
        h_hi[m][col] = __builtin_bit_cast(short, (_Float16)hn);
      }
    }
    __syncthreads();

#pragma unroll
    for (int i = 0; i < 16; ++i) xg[i] = xgn[i];
#pragma unroll
    for (int i = 0; i < 8; ++i) xc[i] = xcn[i];
  }

  for (int q = tid; q < DOCS * 256; q += 512) {
    int m = q >> 8, j = q & 255;
    docv[(size_t)(g0 + m) * 512 + dir * 256 + j] = h_f[m][j];
  }
}

__global__ __launch_bounds__(256) void mlp_head(
    const float* __restrict__ docv, const float* __restrict__ W1,
    const float* __restrict__ b1, const float* __restrict__ W2,
    const float* __restrict__ b2, float* __restrict__ out) {
  const int b = blockIdx.x, j = threadIdx.x;
  __shared__ float hid[256];
  float acc = b1[j];
#pragma unroll 4
  for (int k = 0; k < 512; ++k) acc += docv[b * 512 + k] * W1[k * 256 + j];
  hid[j] = fmaxf(acc, 0.f);
  __syncthreads();
  if (j < 5) {
    float a = b2[j];
#pragma unroll 4
    for (int k = 0; k < 256; ++k) a += hid[k] * W2[k * 5 + j];
    out[b * 5 + j] = a;
  }
}

extern "C" void kernel_launch(void* const* d_in, const int* in_sizes, int n_in,
                              void* d_out, int out_size, void* d_ws, size_t ws_size,
                              hipStream_t stream) {
  const int* X = (const int*)d_in[0];
  const int* L = (const int*)d_in[1];
  const int* L2 = (const int*)d_in[2];
  const float* emb = (const float*)d_in[3];
  const float* sWg_f = (const float*)d_in[4];
  const float* sbg_f = (const float*)d_in[5];
  const float* sWc_f = (const float*)d_in[6];
  const float* sbc_f = (const float*)d_in[7];
  const float* sWg_b = (const float*)d_in[8];
  const float* sbg_b = (const float*)d_in[9];
  const float* sWc_b = (const float*)d_in[10];
  const float* sbc_b = (const float*)d_in[11];
  const float* dWg_f = (const float*)d_in[12];
  const float* dbg_f = (const float*)d_in[13];
  const float* dWc_f = (const float*)d_in[14];
  const float* dbc_f = (const float*)d_in[15];
  const float* dWg_b = (const float*)d_in[16];
  const float* dbg_b = (const float*)d_in[17];
  const float* dWc_b = (const float*)d_in[18];
  const float* dbc_b = (const float*)d_in[19];
  const float* W1 = (const float*)d_in[20];
  const float* b1 = (const float*)d_in[21];
  const float* W2 = (const float*)d_in[22];
  const float* b2 = (const float*)d_in[23];
  float* out = (float*)d_out;

  float* ws = (float*)d_ws;
  float* embProj = ws;                        // 50000*768 f32
  float* xprojD = embProj + 38400000;         // 2048*1536 f32
  float* docv = xprojD + 3145728;             // 64*512 f32
  short* sentHi = (short*)(docv + 32768);     // 2048*256 bf16
  short* sentLo = sentHi + 524288;
  short* BtHi = sentLo + 524288;              // 768*128 bf16
  short* BtLo = BtHi + 98304;
  short* PdTHi = BtLo + 98304;                // 1536*256 bf16
  short* PdTLo = PdTHi + 393216;
  short* DW = PdTLo + 393216;                 // 2*48*512*8 f16

  // weight prep
  hipLaunchKernelGGL(bt_prep, dim3(384), dim3(256), 0, stream,
                     sWg_f, sWc_f, sWg_b, sWc_b, BtHi, BtLo);
  hipLaunchKernelGGL(packdt_prep, dim3(1536), dim3(256), 0, stream,
                     dWg_f, dWc_f, dWg_b, dWc_b, PdTHi, PdTLo);
  hipLaunchKernelGGL(dw_prep, dim3(1536), dim3(256), 0, stream,
                     dWg_f, dWc_f, dWg_b, dWc_b, DW);

  // embProj = emb @ packS  [50000,768] (MFMA split-bf16)
  hipLaunchKernelGGL(emb_gemm, dim3(782), dim3(256), 0, stream,
                     emb, BtHi, BtLo, embProj);

  // sentence bi-GRU -> sentHi/sentLo [2048,256] bf16 planes
  hipLaunchKernelGGL(sent_gru, dim3(128, 2), dim3(256), 0, stream,
                     X, L, embProj,
                     sWg_f, sbg_f, sWc_f, sbc_f,
                     sWg_b, sbg_b, sWc_b, sbc_b, sentHi, sentLo);

  // xprojD = sent @ packD  [2048,1536] (MFMA split-bf16)
  hipLaunchKernelGGL(xproj_gemm, dim3(32, 3), dim3(256), 0, stream,
                     sentHi, sentLo, PdTHi, PdTLo, xprojD);

  // doc bi-GRU -> docv [64,512]
  hipLaunchKernelGGL(doc_gru_mfma, dim3(4, 2), dim3(512), 0, stream,
                     xprojD, L2, DW,
                     dbg_f, dbc_f, dbg_b, dbc_b, docv);

  hipLaunchKernelGGL(mlp_head, dim3(64), dim3(256), 0, stream,
                     docv, W1, b1, W2, b2, out);
}

// Round 9
// 768.289 us; speedup vs baseline: 1.4913x; 1.4913x over previous
//
#include <hip/hip_runtime.h>
#include <cstdint>
#include <cstddef>

// ---------------------------------------------------------------------------
// TreeModel: hierarchical bi-GRU (sentence + doc) + MLP head. Round 9:
//   - REVERT round-8 regression: sent_gru back to __launch_bounds__(256,1)
//     (the (256,2) cap forced VGPR=128 -> 192-reg weight file spilled to
//     scratch: WRITE_SIZE 2->83MB, 247->634us).
//   - Length-sort batching: counting-sort permutation groups sentences
//     (and docs) of similar length per block -> block maxlen ~61 -> ~33
//     steps (1.85x fewer serial GRU steps + gathers). Outputs scatter back
//     through the perm, downstream kernels unchanged.
// ---------------------------------------------------------------------------

typedef __attribute__((ext_vector_type(8))) short bf16x8;     // 8 bf16 = 4 VGPR
typedef __attribute__((ext_vector_type(8))) _Float16 f16x8;   // 8 f16  = 4 VGPR
typedef __attribute__((ext_vector_type(4))) float f32x4;      // C/D frag

__device__ __forceinline__ void split_bf16(float f, short& hi, short& lo) {
  unsigned u = __float_as_uint(f);
  unsigned rb = (u + 0x7FFFu + ((u >> 16) & 1u)) & 0xFFFF0000u;  // RNE
  hi = (short)(rb >> 16);
  float r = f - __uint_as_float(rb);
  unsigned ur = __float_as_uint(r);
  lo = (short)((ur + 0x7FFFu + ((ur >> 16) & 1u)) >> 16);
}

__device__ __forceinline__ float bf2f(short s) {
  return __uint_as_float(((unsigned)(unsigned short)s) << 16);
}

__device__ __forceinline__ float sigm(float x) { return 1.f / (1.f + __expf(-x)); }
__device__ __forceinline__ float tanh_fast(float x) {
  float e = __expf(2.f * x);
  return 1.f - 2.f / (e + 1.f);
}

// Counting-sort permutation by value (values in [0,63]). One block.
__global__ void sort_perm(const int* __restrict__ vals, int* __restrict__ perm, int n) {
  __shared__ int hist[64], base[64];
  int tid = threadIdx.x;
  if (tid < 64) hist[tid] = 0;
  __syncthreads();
  for (int i = tid; i < n; i += blockDim.x) atomicAdd(&hist[vals[i] & 63], 1);
  __syncthreads();
  if (tid == 0) {
    int s = 0;
    for (int v = 0; v < 64; ++v) { base[v] = s; s += hist[v]; }
  }
  __syncthreads();
  for (int i = tid; i < n; i += blockDim.x) {
    int pos = atomicAdd(&base[vals[i] & 63], 1);
    perm[pos] = i;
  }
}

// Build transposed, split-bf16 B for embProj: Bt[n][k], n in [0,768), k in [0,128)
__global__ void bt_prep(const float* __restrict__ sWg_f, const float* __restrict__ sWc_f,
                        const float* __restrict__ sWg_b, const float* __restrict__ sWc_b,
                        short* __restrict__ BtHi, short* __restrict__ BtLo) {
  int i = blockIdx.x * 256 + threadIdx.x;
  if (i >= 768 * 128) return;
  int n = i >> 7, k = i & 127;
  float f;
  if (n < 256) f = sWg_f[k * 256 + n];
  else if (n < 384) f = sWc_f[k * 128 + (n - 256)];
  else if (n < 640) f = sWg_b[k * 256 + (n - 384)];
  else f = sWc_b[k * 128 + (n - 640)];
  short hi, lo;
  split_bf16(f, hi, lo);
  BtHi[i] = hi;
  BtLo[i] = lo;
}

// Transposed split-bf16 planes of doc x-part weights: PdT[n][k], n in [0,1536),
// k in [0,256). n layout: [dWg_f 512 | dWc_f 256 | dWg_b 512 | dWc_b 256].
__global__ void packdt_prep(const float* __restrict__ dWg_f, const float* __restrict__ dWc_f,
                            const float* __restrict__ dWg_b, const float* __restrict__ dWc_b,
                            short* __restrict__ Hi, short* __restrict__ Lo) {
  int i = blockIdx.x * 256 + threadIdx.x;
  if (i >= 1536 * 256) return;
  int n = i >> 8, k = i & 255;
  float f;
  if (n < 512) f = dWg_f[k * 512 + n];
  else if (n < 768) f = dWc_f[k * 256 + (n - 512)];
  else if (n < 1280) f = dWg_b[k * 512 + (n - 768)];
  else f = dWc_b[k * 256 + (n - 1280)];
  short hi, lo;
  split_bf16(f, hi, lo);
  Hi[i] = hi;
  Lo[i] = lo;
}

// Doc h-part weights -> f16, fragment-ordered: DW[dir][f(48)][tid(512)][e(8)].
__global__ void dw_prep(const float* __restrict__ dWg_f, const float* __restrict__ dWc_f,
                        const float* __restrict__ dWg_b, const float* __restrict__ dWc_b,
                        short* __restrict__ DW) {
  int i = blockIdx.x * 256 + threadIdx.x;   // 2*48*512*8 = 393216
  if (i >= 393216) return;
  int e = i & 7;
  int tid = (i >> 3) & 511;
  int dir = i >> 12 >= 48 ? 1 : 0;
  int f = (i >> 12) - dir * 48;
  int w = tid >> 6, g = (tid >> 4) & 3, li = tid & 15;
  const float* Wg = dir ? dWg_b : dWg_f;
  const float* Wc = dir ? dWc_b : dWc_f;
  float v;
  if (f < 32) {
    int nt = f >> 3, kk = f & 7;
    v = Wg[(size_t)(256 + 32 * kk + 8 * g + e) * 512 + 64 * w + 16 * nt + li];
  } else {
    int q = f - 32, ct = q >> 3, kk = q & 7;
    v = Wc[(size_t)(256 + 32 * kk + 8 * g + e) * 256 + 32 * w + 16 * ct + li];
  }
  DW[i] = __builtin_bit_cast(short, (_Float16)v);
}

// ---------------------------------------------------------------------------
// embProj[50000,768] = emb[50000,128] @ packS[128,768], MFMA 3-pass split-bf16.
// ---------------------------------------------------------------------------
__global__ __launch_bounds__(256, 1) void emb_gemm(
    const float* __restrict__ emb, const short* __restrict__ BtHi,
    const short* __restrict__ BtLo, float* __restrict__ C) {
  const int tid = threadIdx.x;
  const int w = tid >> 6, l = tid & 63, li = l & 15, g = l >> 4;
  const int m0 = blockIdx.x * 64;

  bf16x8 ahi[4][4], alo[4][4];
#pragma unroll
  for (int mt = 0; mt < 4; ++mt) {
    int row = m0 + 16 * mt + li;
    if (row > 49999) row = 49999;
    const float* ap = emb + (size_t)row * 128 + 8 * g;
#pragma unroll
    for (int kk = 0; kk < 4; ++kk) {
      float4 v0 = *(const float4*)(ap + 32 * kk);
      float4 v1 = *(const float4*)(ap + 32 * kk + 4);
      float vv[8] = {v0.x, v0.y, v0.z, v0.w, v1.x, v1.y, v1.z, v1.w};
#pragma unroll
      for (int e = 0; e < 8; ++e) {
        short hi, lo;
        split_bf16(vv[e], hi, lo);
        ahi[mt][kk][e] = hi;
        alo[mt][kk][e] = lo;
      }
    }
  }

  f32x4 acc[4][12];
#pragma unroll
  for (int mt = 0; mt < 4; ++mt)
#pragma unroll
    for (int nt = 0; nt < 12; ++nt) acc[mt][nt] = (f32x4){0.f, 0.f, 0.f, 0.f};

#pragma unroll
  for (int nt = 0; nt < 12; ++nt) {
    const int col = 192 * w + 16 * nt + li;
    const short* bh = BtHi + col * 128 + 8 * g;
    const short* bl = BtLo + col * 128 + 8 * g;
    bf16x8 bhi[4], blo[4];
#pragma unroll
    for (int kk = 0; kk < 4; ++kk) {
      bhi[kk] = *(const bf16x8*)(bh + 32 * kk);
      blo[kk] = *(const bf16x8*)(bl + 32 * kk);
    }
#pragma unroll
    for (int kk = 0; kk < 4; ++kk)
#pragma unroll
      for (int mt = 0; mt < 4; ++mt) {
        acc[mt][nt] = __builtin_amdgcn_mfma_f32_16x16x32_bf16(alo[mt][kk], bhi[kk], acc[mt][nt], 0, 0, 0);
        acc[mt][nt] = __builtin_amdgcn_mfma_f32_16x16x32_bf16(ahi[mt][kk], blo[kk], acc[mt][nt], 0, 0, 0);
        acc[mt][nt] = __builtin_amdgcn_mfma_f32_16x16x32_bf16(ahi[mt][kk], bhi[kk], acc[mt][nt], 0, 0, 0);
      }
  }

#pragma unroll
  for (int mt = 0; mt < 4; ++mt)
#pragma unroll
    for (int nt = 0; nt < 12; ++nt) {
      const int col = 192 * w + 16 * nt + li;
#pragma unroll
      for (int r = 0; r < 4; ++r) {
        int row = m0 + 16 * mt + 4 * g + r;
        if (row < 50000) C[(size_t)row * 768 + col] = acc[mt][nt][r];
      }
    }
}

// ---------------------------------------------------------------------------
// xprojD[2048,1536] = sent[2048,256] @ packD[256,1536], MFMA 3-pass split-bf16.
// ---------------------------------------------------------------------------
__global__ __launch_bounds__(256, 1) void xproj_gemm(
    const short* __restrict__ AHi, const short* __restrict__ ALo,
    const short* __restrict__ BtHi, const short* __restrict__ BtLo,
    float* __restrict__ C) {
  const int tid = threadIdx.x;
  const int w = tid >> 6, l = tid & 63, li = l & 15, g = l >> 4;
  const int m0 = blockIdx.x * 64;
  const int n0 = blockIdx.y * 512 + 128 * w;

  f32x4 acc[4][8];
#pragma unroll
  for (int mt = 0; mt < 4; ++mt)
#pragma unroll
    for (int nt = 0; nt < 8; ++nt) acc[mt][nt] = (f32x4){0.f, 0.f, 0.f, 0.f};

#pragma unroll
  for (int kk = 0; kk < 8; ++kk) {
    bf16x8 ah[4], al[4];
#pragma unroll
    for (int mt = 0; mt < 4; ++mt) {
      const int row = m0 + 16 * mt + li;
      ah[mt] = *(const bf16x8*)&AHi[(size_t)row * 256 + 32 * kk + 8 * g];
      al[mt] = *(const bf16x8*)&ALo[(size_t)row * 256 + 32 * kk + 8 * g];
    }
#pragma unroll
    for (int nt = 0; nt < 8; ++nt) {
      const int col = n0 + 16 * nt + li;
      bf16x8 bh = *(const bf16x8*)&BtHi[(size_t)col * 256 + 32 * kk + 8 * g];
      bf16x8 bl = *(const bf16x8*)&BtLo[(size_t)col * 256 + 32 * kk + 8 * g];
#pragma unroll
      for (int mt = 0; mt < 4; ++mt) {
        acc[mt][nt] = __builtin_amdgcn_mfma_f32_16x16x32_bf16(al[mt], bh, acc[mt][nt], 0, 0, 0);
        acc[mt][nt] = __builtin_amdgcn_mfma_f32_16x16x32_bf16(ah[mt], bl, acc[mt][nt], 0, 0, 0);
        acc[mt][nt] = __builtin_amdgcn_mfma_f32_16x16x32_bf16(ah[mt], bh, acc[mt][nt], 0, 0, 0);
      }
    }
  }

#pragma unroll
  for (int mt = 0; mt < 4; ++mt)
#pragma unroll
    for (int nt = 0; nt < 8; ++nt) {
      const int col = n0 + 16 * nt + li;
#pragma unroll
      for (int r = 0; r < 4; ++r) {
        int row = m0 + 16 * mt + 4 * g + r;
        C[(size_t)row * 1536 + col] = acc[mt][nt][r];
      }
    }
}

// ---------------------------------------------------------------------------
// Sentence GRU, MFMA. grid (128,2), block 256, launch_bounds (256,1)
// (weights MUST stay register-resident; (256,2) spilled them in round 8).
// Sentences assigned via length-sorted perm -> block maxlen ~ its quantile.
// ---------------------------------------------------------------------------
#define SENTS 16

__global__ __launch_bounds__(256, 1) void sent_gru(
    const int* __restrict__ X, const int* __restrict__ L,
    const int* __restrict__ perm,
    const float* __restrict__ embProj,
    const float* __restrict__ Wg_f, const float* __restrict__ bg_f,
    const float* __restrict__ Wc_f, const float* __restrict__ bc_f,
    const float* __restrict__ Wg_b, const float* __restrict__ bg_b,
    const float* __restrict__ Wc_b, const float* __restrict__ bc_b,
    short* __restrict__ sentHi, short* __restrict__ sentLo) {
  const int dir = blockIdx.y;
  const int g0 = blockIdx.x * SENTS;
  const int tid = threadIdx.x;
  const int w = tid >> 6, l = tid & 63;
  const int li = l & 15, g = l >> 4;
  const float* Wg = dir ? Wg_b : Wg_f;
  const float* Wc = dir ? Wc_b : Wc_f;
  const float* bgp = dir ? bg_b : bg_f;
  const float* bcp = dir ? bc_b : bc_f;

  __shared__ float xbuf[2][SENTS][384];
  __shared__ float u_f[SENTS][132];
  alignas(16) __shared__ short h_hi[SENTS][136], h_lo[SENTS][136];
  alignas(16) __shared__ short rh_hi[SENTS][136], rh_lo[SENTS][136];
  __shared__ int wid[2][SENTS];
  __shared__ int len_s[SENTS];
  __shared__ int sid_s[SENTS];

  bf16x8 bgh[4][4], bgl[4][4];
  bf16x8 bch[2][4], bcl[2][4];
#pragma unroll
  for (int nt = 0; nt < 4; ++nt)
#pragma unroll
    for (int kk = 0; kk < 4; ++kk) {
      const float* base = Wg + (size_t)(128 + 32 * kk + 8 * g) * 256 + 64 * w + 16 * nt + li;
#pragma unroll
      for (int e = 0; e < 8; ++e) {
        short hi, lo;
        split_bf16(base[(size_t)e * 256], hi, lo);
        bgh[nt][kk][e] = hi; bgl[nt][kk][e] = lo;
      }
    }
#pragma unroll
  for (int ct = 0; ct < 2; ++ct)
#pragma unroll
    for (int kk = 0; kk < 4; ++kk) {
      const float* base = Wc + (size_t)(128 + 32 * kk + 8 * g) * 128 + 32 * w + 16 * ct + li;
#pragma unroll
      for (int e = 0; e < 8; ++e) {
        short hi, lo;
        split_bf16(base[(size_t)e * 128], hi, lo);
        bch[ct][kk][e] = hi; bcl[ct][kk][e] = lo;
      }
    }
  float bgj[4], bcj[2];
#pragma unroll
  for (int nt = 0; nt < 4; ++nt) bgj[nt] = bgp[64 * w + 16 * nt + li];
#pragma unroll
  for (int ct = 0; ct < 2; ++ct) bcj[ct] = bcp[32 * w + 16 * ct + li];

  if (tid < SENTS) {
    int sid = perm[g0 + tid];
    sid_s[tid] = sid;
    int ll = L[sid];
    len_s[tid] = ll;
    wid[0][tid] = X[sid * 64 + (dir ? (ll - 1) : 0)];
    wid[1][tid] = (1 < ll) ? X[sid * 64 + (dir ? (ll - 2) : 1)] : 0;
  }
  for (int q = tid; q < SENTS * 136; q += 256) {
    ((short*)h_hi)[q] = 0; ((short*)h_lo)[q] = 0;
  }
  __syncthreads();

  int lens4[4];
#pragma unroll
  for (int r = 0; r < 4; ++r) lens4[r] = len_s[4 * g + r];
  int maxlen = 0;
#pragma unroll
  for (int m = 0; m < SENTS; ++m) maxlen = max(maxlen, len_s[m]);

  auto prefetch_x = [&](int t) {
    int b = t & 1;
#pragma unroll
    for (int c = 0; c < 6; ++c) {
      int q = tid + 256 * c;
      int m = q / 96, s = q - m * 96;
      const float* src = embProj + (size_t)wid[b][m] * 768 + dir * 384 + s * 4;
      float* dst = (float*)&xbuf[b][0][0] + q * 4;
      __builtin_amdgcn_global_load_lds(
          (const __attribute__((address_space(1))) void*)src,
          (__attribute__((address_space(3))) void*)dst, 16, 0, 0);
    }
  };

  prefetch_x(0);
  __syncthreads();

  for (int t = 0; t < maxlen; ++t) {
    const int cur = t & 1;
    prefetch_x(t + 1);
    if (tid < SENTS) {
      int ll = len_s[tid], tt = t + 2;
      wid[tt & 1][tid] = (tt < ll) ? X[sid_s[tid] * 64 + (dir ? (ll - 1 - tt) : tt)] : 0;
    }

    bf16x8 a_hi[4], a_lo[4];
#pragma unroll
    for (int kk = 0; kk < 4; ++kk) {
      a_hi[kk] = *(const bf16x8*)&h_hi[li][32 * kk + 8 * g];
      a_lo[kk] = *(const bf16x8*)&h_lo[li][32 * kk + 8 * g];
    }
    f32x4 accg[4];
#pragma unroll
    for (int nt = 0; nt < 4; ++nt) {
      const int col = 64 * w + 16 * nt + li;
      f32x4 c;
#pragma unroll
      for (int r = 0; r < 4; ++r) c[r] = bgj[nt] + xbuf[cur][4 * g + r][col];
#pragma unroll
      for (int kk = 0; kk < 4; ++kk) {
        c = __builtin_amdgcn_mfma_f32_16x16x32_bf16(a_hi[kk], bgh[nt][kk], c, 0, 0, 0);
        c = __builtin_amdgcn_mfma_f32_16x16x32_bf16(a_hi[kk], bgl[nt][kk], c, 0, 0, 0);
        c = __builtin_amdgcn_mfma_f32_16x16x32_bf16(a_lo[kk], bgh[nt][kk], c, 0, 0, 0);
      }
      accg[nt] = c;
    }
    if (w < 2) {
#pragma unroll
      for (int nt = 0; nt < 4; ++nt) {
        const int col = 64 * w + 16 * nt + li;
#pragma unroll
        for (int r = 0; r < 4; ++r) {
          const int row = 4 * g + r;
          float s = sigm(accg[nt][r]);
          float hold = bf2f(h_hi[row][col]) + bf2f(h_lo[row][col]);
          float rh = s * hold;
          short hi, lo;
          split_bf16(rh, hi, lo);
          rh_hi[row][col] = hi;
          rh_lo[row][col] = lo;
        }
      }
    } else {
#pragma unroll
      for (int nt = 0; nt < 4; ++nt) {
        const int col = 64 * (w - 2) + 16 * nt + li;
#pragma unroll
        for (int r = 0; r < 4; ++r) {
          u_f[4 * g + r][col] = sigm(accg[nt][r]);
        }
      }
    }
    __syncthreads();

    bf16x8 ra_hi[4], ra_lo[4];
#pragma unroll
    for (int kk = 0; kk < 4; ++kk) {
      ra_hi[kk] = *(const bf16x8*)&rh_hi[li][32 * kk + 8 * g];
      ra_lo[kk] = *(const bf16x8*)&rh_lo[li][32 * kk + 8 * g];
    }
#pragma unroll
    for (int ct = 0; ct < 2; ++ct) {
      const int col = 32 * w + 16 * ct + li;
      f32x4 c;
#pragma unroll
      for (int r = 0; r < 4; ++r) c[r] = bcj[ct] + xbuf[cur][4 * g + r][256 + col];
#pragma unroll
      for (int kk = 0; kk < 4; ++kk) {
        c = __builtin_amdgcn_mfma_f32_16x16x32_bf16(ra_hi[kk], bch[ct][kk], c, 0, 0, 0);
        c = __builtin_amdgcn_mfma_f32_16x16x32_bf16(ra_hi[kk], bcl[ct][kk], c, 0, 0, 0);
        c = __builtin_amdgcn_mfma_f32_16x16x32_bf16(ra_lo[kk], bch[ct][kk], c, 0, 0, 0);
      }
#pragma unroll
      for (int r = 0; r < 4; ++r) {
        const int row = 4 * g + r;
        float cand = tanh_fast(c[r]);
        float u = u_f[row][col];
        float hold = bf2f(h_hi[row][col]) + bf2f(h_lo[row][col]);
        float hn = u * hold + (1.f - u) * cand;
        hn = (t < lens4[r]) ? hn : hold;
        short hi, lo;
        split_bf16(hn, hi, lo);
        h_hi[row][col] = hi;
        h_lo[row][col] = lo;
      }
    }
    __syncthreads();
  }

  for (int q = tid; q < SENTS * 128; q += 256) {
    int m = q >> 7, j = q & 127;
    size_t o = (size_t)sid_s[m] * 256 + dir * 128 + j;
    sentHi[o] = h_hi[m][j];
    sentLo[o] = h_lo[m][j];
  }
}

// ---------------------------------------------------------------------------
// Doc GRU, f16 MFMA v5 + length-sorted docs. grid (4, 2), block 512.
// Weights from fragment-ordered f16 pack (coalesced b128 loads).
// ---------------------------------------------------------------------------
#define DOCS 16

__global__ __launch_bounds__(512, 1) void doc_gru_mfma(
    const float* __restrict__ xprojD, const int* __restrict__ L2,
    const int* __restrict__ perm2,
    const short* __restrict__ DW,
    const float* __restrict__ dbg_f, const float* __restrict__ dbc_f,
    const float* __restrict__ dbg_b, const float* __restrict__ dbc_b,
    float* __restrict__ docv) {
  const int dir = blockIdx.y;
  const int g0 = blockIdx.x * DOCS;
  const int tid = threadIdx.x;
  const int w = tid >> 6, l = tid & 63, li = l & 15, g = l >> 4;
  const float* bgp = dir ? dbg_b : dbg_f;
  const float* bcp = dir ? dbc_b : dbc_f;
  const int xoff = dir ? 768 : 0;

  alignas(16) __shared__ short h_hi[DOCS][264];
  alignas(16) __shared__ short rh_hi[DOCS][264];
  __shared__ float h_f[DOCS][256], u_f[DOCS][256];
  __shared__ int len_s[DOCS];
  __shared__ int did_s[DOCS];

  f16x8 wg[4][8];
  f16x8 wc[2][8];
  const short* DWp = DW + (size_t)dir * 48 * 512 * 8;
#pragma unroll
  for (int nt = 0; nt < 4; ++nt)
#pragma unroll
    for (int kk = 0; kk < 8; ++kk) {
      int f = nt * 8 + kk;
      wg[nt][kk] = *(const f16x8*)&DWp[((size_t)f * 512 + tid) * 8];
      asm volatile("" : "+v"(wg[nt][kk]));
    }
#pragma unroll
  for (int ct = 0; ct < 2; ++ct)
#pragma unroll
    for (int kk = 0; kk < 8; ++kk) {
      int f = 32 + ct * 8 + kk;
      wc[ct][kk] = *(const f16x8*)&DWp[((size_t)f * 512 + tid) * 8];
      asm volatile("" : "+v"(wc[ct][kk]));
    }
  float bgj[4], bcj[2];
#pragma unroll
  for (int nt = 0; nt < 4; ++nt) bgj[nt] = bgp[64 * w + 16 * nt + li];
#pragma unroll
  for (int ct = 0; ct < 2; ++ct) bcj[ct] = bcp[32 * w + 16 * ct + li];

  if (tid < DOCS) {
    int d = perm2[g0 + tid];
    did_s[tid] = d;
    len_s[tid] = L2[d];
  }
  for (int q = tid; q < DOCS * 264; q += 512) ((short*)h_hi)[q] = 0;
  for (int q = tid; q < DOCS * 256; q += 512) {
    ((float*)h_f)[q] = 0.f; ((float*)u_f)[q] = 0.f;
  }
  __syncthreads();

  int lens4[4], dids4[4];
#pragma unroll
  for (int r = 0; r < 4; ++r) {
    lens4[r] = len_s[4 * g + r];
    dids4[r] = did_s[4 * g + r];
  }
  int maxlen = 0;
#pragma unroll
  for (int m = 0; m < DOCS; ++m) maxlen = max(maxlen, len_s[m]);

  auto xrow = [&](int r, int t) -> size_t {
    int ti = dir ? max(lens4[r] - 1 - t, 0) : min(t, 31);
    return ((size_t)dids4[r] * 32 + ti) * 1536 + xoff;
  };

  float xg[16], xc[8], xgn[16], xcn[8];
#pragma unroll
  for (int r = 0; r < 4; ++r) {
    size_t xb = xrow(r, 0);
#pragma unroll
    for (int nt = 0; nt < 4; ++nt) xg[nt * 4 + r] = xprojD[xb + 64 * w + 16 * nt + li];
#pragma unroll
    for (int ct = 0; ct < 2; ++ct) xc[ct * 4 + r] = xprojD[xb + 512 + 32 * w + 16 * ct + li];
  }

  for (int t = 0; t < maxlen; ++t) {
    f32x4 acc[4];
#pragma unroll
    for (int nt = 0; nt < 4; ++nt)
#pragma unroll
      for (int r = 0; r < 4; ++r) acc[nt][r] = bgj[nt] + xg[nt * 4 + r];
    f32x4 acc2[2];
#pragma unroll
    for (int ct = 0; ct < 2; ++ct)
#pragma unroll
      for (int r = 0; r < 4; ++r) acc2[ct][r] = bcj[ct] + xc[ct * 4 + r];

#pragma unroll
    for (int r = 0; r < 4; ++r) {
      size_t xb = xrow(r, t + 1);
#pragma unroll
      for (int nt = 0; nt < 4; ++nt) xgn[nt * 4 + r] = xprojD[xb + 64 * w + 16 * nt + li];
#pragma unroll
      for (int ct = 0; ct < 2; ++ct) xcn[ct * 4 + r] = xprojD[xb + 512 + 32 * w + 16 * ct + li];
    }

#pragma unroll
    for (int c = 0; c < 8; ++c) {
      f16x8 ah = *(const f16x8*)&h_hi[li][32 * c + 8 * g];
#pragma unroll
      for (int nt = 0; nt < 4; ++nt)
        acc[nt] = __builtin_amdgcn_mfma_f32_16x16x32_f16(ah, wg[nt][c], acc[nt], 0, 0, 0);
    }
    if (w < 4) {
#pragma unroll
      for (int nt = 0; nt < 4; ++nt) {
        const int col = 64 * w + 16 * nt + li;
#pragma unroll
        for (int r = 0; r < 4; ++r) {
          const int m = 4 * g + r;
          float s = sigm(acc[nt][r]);
          float rh = s * h_f[m][col];
          rh_hi[m][col] = __builtin_bit_cast(short, (_Float16)rh);
        }
      }
    } else {
#pragma unroll
      for (int nt = 0; nt < 4; ++nt) {
        const int col = 64 * (w - 4) + 16 * nt + li;
#pragma unroll
        for (int r = 0; r < 4; ++r) u_f[4 * g + r][col] = sigm(acc[nt][r]);
      }
    }
    __syncthreads();

#pragma unroll
    for (int c = 0; c < 8; ++c) {
      f16x8 rah = *(const f16x8*)&rh_hi[li][32 * c + 8 * g];
#pragma unroll
      for (int ct = 0; ct < 2; ++ct)
        acc2[ct] = __builtin_amdgcn_mfma_f32_16x16x32_f16(rah, wc[ct][c], acc2[ct], 0, 0, 0);
    }
#pragma unroll
    for (int ct = 0; ct < 2; ++ct) {
      const int col = 32 * w + 16 * ct + li;
#pragma unroll
      for (int r = 0; r < 4; ++r) {
        const int m = 4 * g + r;
        float cand = tanh_fast(acc2[ct][r]);
        float u = u_f[m][col];
        float hold = h_f[m][col];
        float hn = u * hold + (1.f - u) * cand;
        hn = (t < lens4[r]) ? hn : hold;
        h_f[m][col] = hn;
        h_hi[m][col] = __builtin_bit_cast(short, (_Float16)hn);
      }
    }
    __syncthreads();

#pragma unroll
    for (int i = 0; i < 16; ++i) xg[i] = xgn[i];
#pragma unroll
    for (int i = 0; i < 8; ++i) xc[i] = xcn[i];
  }

  for (int q = tid; q < DOCS * 256; q += 512) {
    int m = q >> 8, j = q & 255;
    docv[(size_t)did_s[m] * 512 + dir * 256 + j] = h_f[m][j];
  }
}

__global__ __launch_bounds__(256) void mlp_head(
    const float* __restrict__ docv, const float* __restrict__ W1,
    const float* __restrict__ b1, const float* __restrict__ W2,
    const float* __restrict__ b2, float* __restrict__ out) {
  const int b = blockIdx.x, j = threadIdx.x;
  __shared__ float hid[256];
  float acc = b1[j];
#pragma unroll 4
  for (int k = 0; k < 512; ++k) acc += docv[b * 512 + k] * W1[k * 256 + j];
  hid[j] = fmaxf(acc, 0.f);
  __syncthreads();
  if (j < 5) {
    float a = b2[j];
#pragma unroll 4
    for (int k = 0; k < 256; ++k) a += hid[k] * W2[k * 5 + j];
    out[b * 5 + j] = a;
  }
}

extern "C" void kernel_launch(void* const* d_in, const int* in_sizes, int n_in,
                              void* d_out, int out_size, void* d_ws, size_t ws_size,
                              hipStream_t stream) {
  const int* X = (const int*)d_in[0];
  const int* L = (const int*)d_in[1];
  const int* L2 = (const int*)d_in[2];
  const float* emb = (const float*)d_in[3];
  const float* sWg_f = (const float*)d_in[4];
  const float* sbg_f = (const float*)d_in[5];
  const float* sWc_f = (const float*)d_in[6];
  const float* sbc_f = (const float*)d_in[7];
  const float* sWg_b = (const float*)d_in[8];
  const float* sbg_b = (const float*)d_in[9];
  const float* sWc_b = (const float*)d_in[10];
  const float* sbc_b = (const float*)d_in[11];
  const float* dWg_f = (const float*)d_in[12];
  const float* dbg_f = (const float*)d_in[13];
  const float* dWc_f = (const float*)d_in[14];
  const float* dbc_f = (const float*)d_in[15];
  const float* dWg_b = (const float*)d_in[16];
  const float* dbg_b = (const float*)d_in[17];
  const float* dWc_b = (const float*)d_in[18];
  const float* dbc_b = (const float*)d_in[19];
  const float* W1 = (const float*)d_in[20];
  const float* b1 = (const float*)d_in[21];
  const float* W2 = (const float*)d_in[22];
  const float* b2 = (const float*)d_in[23];
  float* out = (float*)d_out;

  float* ws = (float*)d_ws;
  float* embProj = ws;                        // 50000*768 f32
  float* xprojD = embProj + 38400000;         // 2048*1536 f32
  float* docv = xprojD + 3145728;             // 64*512 f32
  short* sentHi = (short*)(docv + 32768);     // 2048*256 bf16
  short* sentLo = sentHi + 524288;
  short* BtHi = sentLo + 524288;              // 768*128 bf16
  short* BtLo = BtHi + 98304;
  short* PdTHi = BtLo + 98304;                // 1536*256 bf16
  short* PdTLo = PdTHi + 393216;
  short* DW = PdTLo + 393216;                 // 2*48*512*8 f16
  int* perm = (int*)(DW + 393216);            // 2048 ints
  int* perm2 = perm + 2048;                   // 64 ints

  // length-sort permutations (sentences, docs)
  hipLaunchKernelGGL(sort_perm, dim3(1), dim3(1024), 0, stream, L, perm, 2048);
  hipLaunchKernelGGL(sort_perm, dim3(1), dim3(1024), 0, stream, L2, perm2, 64);

  // weight prep
  hipLaunchKernelGGL(bt_prep, dim3(384), dim3(256), 0, stream,
                     sWg_f, sWc_f, sWg_b, sWc_b, BtHi, BtLo);
  hipLaunchKernelGGL(packdt_prep, dim3(1536), dim3(256), 0, stream,
                     dWg_f, dWc_f, dWg_b, dWc_b, PdTHi, PdTLo);
  hipLaunchKernelGGL(dw_prep, dim3(1536), dim3(256), 0, stream,
                     dWg_f, dWc_f, dWg_b, dWc_b, DW);

  // embProj = emb @ packS  [50000,768] (MFMA split-bf16)
  hipLaunchKernelGGL(emb_gemm, dim3(782), dim3(256), 0, stream,
                     emb, BtHi, BtLo, embProj);

  // sentence bi-GRU -> sentHi/sentLo [2048,256] bf16 planes
  hipLaunchKernelGGL(sent_gru, dim3(128, 2), dim3(256), 0, stream,
                     X, L, perm, embProj,
                     sWg_f, sbg_f, sWc_f, sbc_f,
                     sWg_b, sbg_b, sWc_b, sbc_b, sentHi, sentLo);

  // xprojD = sent @ packD  [2048,1536] (MFMA split-bf16)
  hipLaunchKernelGGL(xproj_gemm, dim3(32, 3), dim3(256), 0, stream,
                     sentHi, sentLo, PdTHi, PdTLo, xprojD);

  // doc bi-GRU -> docv [64,512]
  hipLaunchKernelGGL(doc_gru_mfma, dim3(4, 2), dim3(512), 0, stream,
                     xprojD, L2, perm2, DW,
                     dbg_f, dbc_f, dbg_b, dbc_b, docv);

  hipLaunchKernelGGL(mlp_head, dim3(64), dim3(256), 0, stream,
                     docv, W1, b1, W2, b2, out);
}